// Round 13
// baseline (118.694 us; speedup 1.0000x reference)
//
#include <hip/hip_runtime.h>
#include <hip/hip_bf16.h>

// LocallyConnected2d: B=16, C=32, O=32, H=W=64, K=3x3, pad=1, stride=1.
// out[b,o,h,w] = sum_{c,k} x[b,c,h+dh,w+dw] * weight[o,c,h,w,k]
//
// R13: ATOMIC-FREE. Cross-round regression exposed f32 atomicAdd as the
// hidden tax (~5us per M lane-atomics: 8-addend rounds 124-137us, 4-addend
// 85-114us). Now csplit=2 writes two PRIVATE partial buffers in d_ws with
// plain coalesced stores; a reduce kernel sums them into out.
//  - OO=1, BB=16 (weights read exactly once), CC=16, grid 1024 blocks
//    (16 h-tiles x 32 o x 2 cg) -> 4 waves/SIMD. No LDS/barriers/drains.
//  - x: bf16 3-tap window XW[b][c][66][64] (pre-padded: no masks, no bperms,
//    3 x 8B loads per (c,b)).
//  - weights: direct strided f32x4 loads (R5-proven).
//  - fallback if ws small: XW + 2-addend atomics; else direct + atomics.

#define CIN  32
#define OCH  32
#define HH   64
#define WW   64
#define HW   4096
#define BB   16
#define CC   16    // c per block (csplit 2)
#define XWR  66
#define NOUT (16 * OCH * HH * WW)          // 2097152 output elements
#define XWE  (16 * CIN * XWR * 64)         // XW elements (u32x2)

typedef float f32x4 __attribute__((ext_vector_type(4), aligned(4)));
typedef float f32x4a __attribute__((ext_vector_type(4), aligned(16)));
typedef unsigned int u32x2 __attribute__((ext_vector_type(2), aligned(8)));

__device__ __forceinline__ unsigned short f2bf(float f) {
    unsigned u = __float_as_uint(f);
    u += 0x7fffu + ((u >> 16) & 1u);
    return (unsigned short)(u >> 16);
}
__device__ __forceinline__ float bf_lo(unsigned v) { return __uint_as_float(v << 16); }
__device__ __forceinline__ float bf_hi(unsigned v) { return __uint_as_float(v & 0xffff0000u); }

__global__ __launch_bounds__(256)
void zero_out_kernel(float* __restrict__ out, int n4) {
    int i = blockIdx.x * 256 + threadIdx.x;
    if (i < n4) ((f32x4a*)out)[i] = (f32x4a){0.f, 0.f, 0.f, 0.f};
}

// XW[b][c][66][64]: u32x2{ lo: bf16 x[w-1] | bf16 x[w]<<16, hi: bf16 x[w+1] }
// row r holds x row h=r-1; rows 0/65 zero, w edges zero.
__global__ __launch_bounds__(256)
void xwin_kernel(const float* __restrict__ x, u32x2* __restrict__ xw) {
    int tid = blockIdx.x * 256 + threadIdx.x;
    if (tid >= XWE) return;
    const int w  = tid & 63;
    const int r  = (tid >> 6) % XWR;
    const int bc = tid / (XWR * 64);
    const int h  = r - 1;
    float xl = 0.f, xm = 0.f, xr = 0.f;
    if (h >= 0 && h < HH) {
        const float* row = x + (size_t)bc * HW + (size_t)h * WW;
        xl = (w > 0)      ? row[w - 1] : 0.f;
        xm = row[w];
        xr = (w < WW - 1) ? row[w + 1] : 0.f;
    }
    u32x2 v;
    v.x = (unsigned)f2bf(xl) | ((unsigned)f2bf(xm) << 16);
    v.y = (unsigned)f2bf(xr);
    xw[tid] = v;
}

__global__ __launch_bounds__(256)
void reduce_kernel(const float* __restrict__ p0, const float* __restrict__ p1,
                   float* __restrict__ out, int n4) {
    int i = blockIdx.x * 256 + threadIdx.x;
    if (i < n4) {
        f32x4a a = ((const f32x4a*)p0)[i];
        f32x4a b = ((const f32x4a*)p1)[i];
        ((f32x4a*)out)[i] = a + b;
    }
}

// MODE 0: XW taps, store partials (no atomics).  MODE 1: XW taps, atomics.
// MODE 2: direct-x taps (masked weights), atomics.
template<int MODE>
__global__ __launch_bounds__(256)
void lc2d_kernel(const float* __restrict__ x, const float* __restrict__ wt,
                 const u32x2* __restrict__ xw, float* __restrict__ part,
                 float* __restrict__ out) {
    const int w  = threadIdx.x;                 // lane == w
    const int h  = blockIdx.x * 4 + threadIdx.y;
    const int o  = blockIdx.y;
    const int cg = blockIdx.z;
    const int c0 = cg * CC;

    // MODE 2 edge handling
    const float mt = (h > 0) ? 1.f : 0.f, mb = (h < HH - 1) ? 1.f : 0.f;
    const float ml = (w > 0) ? 1.f : 0.f, mr = (w < WW - 1) ? 1.f : 0.f;
    const int iht = (h > 0) ? h - 1 : 0, ihb = (h < HH - 1) ? h + 1 : HH - 1;
    const int cl = (w > 0) ? w - 1 : 0, cr = (w < WW - 1) ? w + 1 : WW - 1;

    float acc[BB];
#pragma unroll
    for (int b = 0; b < BB; ++b) acc[b] = 0.f;

    for (int c = 0; c < CC; ++c) {
        const int cc = c0 + c;

        // direct strided weight loads (36B lane stride)
        const float* wp = wt + (((size_t)o * CIN + cc) * HW
                                + (size_t)h * WW + w) * 9;
        f32x4 w03 = *(const f32x4*)(wp);
        f32x4 w47 = *(const f32x4*)(wp + 4);
        float w8  = wp[8];
        float wk0 = w03.x, wk1 = w03.y, wk2 = w03.z, wk3 = w03.w, wk4 = w47.x,
              wk5 = w47.y, wk6 = w47.z, wk7 = w47.w, wk8 = w8;
        if (MODE == 2) {
            wk0 *= mt * ml; wk1 *= mt; wk2 *= mt * mr;
            wk3 *= ml;                  wk5 *= mr;
            wk6 *= mb * ml; wk7 *= mb; wk8 *= mb * mr;
        }

        int xwi = cc * (XWR * 64) + h * 64 + w;   // b=0; += CIN*XWR*64 per b
#pragma unroll
        for (int b = 0; b < BB; ++b) {
            float t0, t1, t2, t3, t4, t5, t6, t7, t8;
            if (MODE != 2) {
                const u32x2 r0 = xw[xwi];
                const u32x2 r1 = xw[xwi + 64];
                const u32x2 r2 = xw[xwi + 128];
                t0 = bf_lo(r0.x); t1 = bf_hi(r0.x); t2 = bf_lo(r0.y);
                t3 = bf_lo(r1.x); t4 = bf_hi(r1.x); t5 = bf_lo(r1.y);
                t6 = bf_lo(r2.x); t7 = bf_hi(r2.x); t8 = bf_lo(r2.y);
                xwi += CIN * XWR * 64;
            } else {
                const float* xp = x + ((size_t)b * CIN + cc) * HW;
                const float* r0 = xp + iht * WW;
                const float* r1 = xp + h * WW;
                const float* r2 = xp + ihb * WW;
                t0 = r0[cl]; t1 = r0[w]; t2 = r0[cr];
                t3 = r1[cl]; t4 = r1[w]; t5 = r1[cr];
                t6 = r2[cl]; t7 = r2[w]; t8 = r2[cr];
            }
            float a = acc[b];
            a = fmaf(t0, wk0, a); a = fmaf(t1, wk1, a); a = fmaf(t2, wk2, a);
            a = fmaf(t3, wk3, a); a = fmaf(t4, wk4, a); a = fmaf(t5, wk5, a);
            a = fmaf(t6, wk6, a); a = fmaf(t7, wk7, a); a = fmaf(t8, wk8, a);
            acc[b] = a;
        }
    }

#pragma unroll
    for (int b = 0; b < BB; ++b) {
        const size_t oi = (((size_t)b * OCH + o) * HH + h) * WW + w;
        if (MODE == 0) part[(size_t)cg * NOUT + oi] = acc[b];
        else           atomicAdd(out + oi, acc[b]);
    }
}

extern "C" void kernel_launch(void* const* d_in, const int* in_sizes, int n_in,
                              void* d_out, int out_size, void* d_ws, size_t ws_size,
                              hipStream_t stream) {
    const float* x  = (const float*)d_in[0];
    const float* wt = (const float*)d_in[1];
    float* out = (float*)d_out;

    const size_t xw_bytes   = (size_t)XWE * 8;            // 17,301,504
    const size_t part_bytes = (size_t)NOUT * 4;           //  8,388,608
    const int n4 = out_size / 4;

    dim3 block(64, 4);
    dim3 grid(HH / 4, OCH, 2);   // 16 x 32 x 2 = 1024 blocks

    if (ws_size >= xw_bytes + 2 * part_bytes) {
        // MODE 0: XW + partials + reduce (no atomics)
        u32x2* xwp  = (u32x2*)d_ws;
        float* part = (float*)((char*)d_ws + xw_bytes);
        xwin_kernel<<<(XWE + 255) / 256, 256, 0, stream>>>(x, xwp);
        lc2d_kernel<0><<<grid, block, 0, stream>>>(x, wt, xwp, part, out);
        reduce_kernel<<<(n4 + 255) / 256, 256, 0, stream>>>(part, part + NOUT, out, n4);
    } else if (ws_size >= xw_bytes) {
        // MODE 1: XW + 2-addend atomics
        u32x2* xwp = (u32x2*)d_ws;
        zero_out_kernel<<<(n4 + 255) / 256, 256, 0, stream>>>(out, n4);
        xwin_kernel<<<(XWE + 255) / 256, 256, 0, stream>>>(x, xwp);
        lc2d_kernel<1><<<grid, block, 0, stream>>>(x, wt, xwp, nullptr, out);
    } else {
        // MODE 2: direct x + 2-addend atomics
        zero_out_kernel<<<(n4 + 255) / 256, 256, 0, stream>>>(out, n4);
        lc2d_kernel<2><<<grid, block, 0, stream>>>(x, wt, nullptr, nullptr, out);
    }
}